// Round 3
// baseline (436.063 us; speedup 1.0000x reference)
//
#include <hip/hip_runtime.h>
#include <hip/hip_bf16.h>

#define HIDDEN  128
#define NUM_RBF 50
#define CUTOFF  5.0f
#define INV_WIDTH (49.0f / 5.0f)
#define OFF_STEP  (5.0f / 49.0f)
#define PI_F 3.14159265358979f

typedef __attribute__((ext_vector_type(8))) short short8;   // 8 bf16 (4 VGPR)
typedef __attribute__((ext_vector_type(4))) float floatx4;  // MFMA acc

// round-half-up bf16 conversion: 2 VALU ops (extra error <= 1/2 ULP on staged
// intermediates only — absmax margin 0.031 vs 0.108 threshold).
__device__ __forceinline__ unsigned short f2bf(float x) {
    union { float f; unsigned int u; } v; v.f = x;
    return (unsigned short)((v.u + 0x8000u) >> 16);
}

// unpack one bf16 of a packed pair to float (hi is compile-time)
__device__ __forceinline__ float bfpair(unsigned int p, int hi) {
    union { unsigned int u; float f; } v;
    v.u = hi ? (p & 0xffff0000u) : (p << 16);
    return v.f;
}

__device__ __forceinline__ float silu(float x) {
    return x / (1.0f + __expf(-x));
}

// XOR-swizzled half-index into a [rows][128] bf16 tile (256B rows): 16B slots
// XORed with row&7 (m201 st_16x32 pattern) — fragment/walk reads land ~2-way
// bank-aliased (free per m136) with NO padding.
__device__ __forceinline__ int swz(int row, int k) {
    return (row << 7) + (((k >> 3) ^ (row & 7)) << 3) + (k & 7);
}

// same idea for [rows][32] bf16 tiles (64B rows, 4 slots, XOR row&3)
__device__ __forceinline__ int swz32(int row, int k) {
    return (row << 5) + (((k >> 3) ^ (row & 3)) << 3) + (k & 7);
}

// ---------------------------------------------------------------------------
// Counting-sort pipeline (scratch lives in d_out; node kernel overwrites d_out
// only at the very end). Hierarchical scan: local 256-bin scans + top scan.
// ---------------------------------------------------------------------------
__global__ void hist_kernel(const int* __restrict__ ei, int* __restrict__ cnt,
                            int n_nodes, int n_edges)
{
    for (int e = blockIdx.x * blockDim.x + threadIdx.x; e < n_edges;
         e += gridDim.x * blockDim.x) {
        const int r = min(max(ei[e], 0), n_nodes - 1);
        atomicAdd(&cnt[r], 1);
    }
}

__global__ __launch_bounds__(256) void scanA_kernel(const int* __restrict__ cnt,
                                                    int* __restrict__ cursor,
                                                    int* __restrict__ btot,
                                                    int nb)
{
    __shared__ int s[256];
    const int t = threadIdx.x;
    const int i = blockIdx.x * 256 + t;
    const int v = (i < nb) ? cnt[i] : 0;
    s[t] = v;
    __syncthreads();
#pragma unroll
    for (int off = 1; off < 256; off <<= 1) {
        const int u = (t >= off) ? s[t - off] : 0;
        __syncthreads();
        s[t] += u;
        __syncthreads();
    }
    if (i < nb) cursor[i] = s[t] - v;           // local exclusive prefix
    if (t == 255) btot[blockIdx.x] = s[255];    // segment total
}

__global__ __launch_bounds__(256) void scanB_kernel(const int* __restrict__ btot,
                                                    int* __restrict__ boff,
                                                    int nblk)
{
    __shared__ int s[256];
    const int t = threadIdx.x;
    const int v = (t < nblk) ? btot[t] : 0;
    s[t] = v;
    __syncthreads();
#pragma unroll
    for (int off = 1; off < 256; off <<= 1) {
        const int u = (t >= off) ? s[t - off] : 0;
        __syncthreads();
        s[t] += u;
        __syncthreads();
    }
    if (t < nblk) boff[t] = s[t] - v;
}

// One 16B record per sorted edge: {row, col, dist, pad}. Single cache line
// touched per random-position write; the edge kernel's meta prefetch is one
// coalesced float4 load.
__global__ void scatter_kernel(const int* __restrict__ ei,
                               const float* __restrict__ pos,
                               int* __restrict__ cursor,
                               const int* __restrict__ boff,
                               float4* __restrict__ emeta,
                               int n_nodes, int n_edges)
{
    for (int e = blockIdx.x * blockDim.x + threadIdx.x; e < n_edges;
         e += gridDim.x * blockDim.x) {
        const int r = min(max(ei[e], 0), n_nodes - 1);
        const int c = min(max(ei[n_edges + e], 0), n_nodes - 1);
        const float dx = pos[r * 3 + 0] - pos[c * 3 + 0];
        const float dy = pos[r * 3 + 1] - pos[c * 3 + 1];
        const float dz = pos[r * 3 + 2] - pos[c * 3 + 2];
        const float dist = sqrtf(dx * dx + dy * dy + dz * dz + 1e-8f);
        const int p = boff[r >> 8] + atomicAdd(&cursor[r], 1);
        emeta[p] = make_float4(__int_as_float(r), __int_as_float(c), dist, 0.0f);
    }
}

// ---------------------------------------------------------------------------
// Edge kernel: 512 thr = 8 waves sharing fw2T/fw1T; each wave owns 16-edge
// tiles (grid-stride).
// LDS budget (round-2 post-mortem): 2x80KB=160KB exact-fit FAILED (occupancy
// 22% = 1 block/CU); round-1's 2x64KB=128KB was resident (46%). So target
// <=72KB: fw2T 32KB + fw1T-hi 8KB + tbuf 32KB = 72KB -> 2 blocks/CU.
// VGPR: fw1 kit-0 frags (k=0..31, 32 VGPRs) back in registers — round-0
// measured 140 demand with BOTH kits in regs; packed hv/bias since saved 24,
// so one kit fits under the 128 cap of __launch_bounds__(512,2) (2nd arg =
// min BLOCKS/CU, CUDA semantics — round-1 post-mortem). kit-1 (k=32..63,
// only 18 nonzero rows) stays in LDS as a 128x32 swizzled tile.
// Spill tripwire: FETCH_SIZE must stay ~142MB.
// ---------------------------------------------------------------------------
template<bool SORTED>
__global__ __launch_bounds__(512, 2) void edge_mfma_kernel(
    const float* __restrict__ h,
    const float* __restrict__ pos,
    const int* __restrict__ ei,
    const float4* __restrict__ emeta,
    const float* __restrict__ fw1,
    const float* __restrict__ fb1,
    const float* __restrict__ fw2,
    const float* __restrict__ fb2,
    float* __restrict__ agg,
    int n_nodes, int n_edges)
{
    __shared__ __attribute__((aligned(16))) unsigned short fw2T[128 * 128];
    __shared__ __attribute__((aligned(16))) unsigned short fw1T[128 * 32];
    __shared__ __attribute__((aligned(16))) unsigned short tbuf[8 * 16 * 128];

    const int tid  = threadIdx.x;
    const int wave = tid >> 6;
    const int lane = tid & 63;
    const int l15  = lane & 15;
    const int quad = lane >> 4;

    // stage fw2 transposed+swizzled (bf16): fw2T[(n,k)] = fw2[k][n]
    for (int idx = tid; idx < HIDDEN * HIDDEN; idx += 512) {
        const int k = idx >> 7, n = idx & 127;
        fw2T[swz(n, k)] = f2bf(fw2[idx]);
    }
    // stage fw1 rows k=32..63 transposed+swizzled (zero rows k>=50):
    // fw1T[(n,k')] = fw1[k'+32][n]
    for (int idx = tid; idx < HIDDEN * 32; idx += 512) {
        const int n = idx >> 5, k = idx & 31;
        const float v = (k + 32 < NUM_RBF) ? fw1[(k + 32) * HIDDEN + n] : 0.0f;
        fw1T[swz32(n, k)] = f2bf(v);
    }

    // fw1 kit-0 B-fragments in registers (k = quad*8+j, all < 32 < NUM_RBF)
    short8 b10[8];
#pragma unroll
    for (int nt = 0; nt < 8; ++nt) {
        short8 f;
#pragma unroll
        for (int j = 0; j < 8; ++j) {
            const int k = quad * 8 + j;
            f[j] = (short)f2bf(fw1[k * HIDDEN + nt * 16 + l15]);
        }
        b10[nt] = f;
    }

    // biases packed bf16 (8 VGPR instead of 16)
    unsigned int fb1p[4], fb2p[4];
#pragma unroll
    for (int p = 0; p < 4; ++p) {
        fb1p[p] = ((unsigned int)f2bf(fb1[(p * 2 + 1) * 16 + l15]) << 16) |
                  (unsigned int)f2bf(fb1[(p * 2) * 16 + l15]);
        fb2p[p] = ((unsigned int)f2bf(fb2[(p * 2 + 1) * 16 + l15]) << 16) |
                  (unsigned int)f2bf(fb2[(p * 2) * 16 + l15]);
    }

    __syncthreads();   // fw2T/fw1T ready; no barriers inside the loop

    unsigned short* twave = &tbuf[wave * 16 * 128];
    const int tiles = (n_edges + 15) >> 4;
    const int tstride = gridDim.x * 8;
    int tile = blockIdx.x * 8 + wave;

    // ---- prefetch first tile's meta (sorted path) ----
    float4 nm = make_float4(0.0f, 0.0f, 0.0f, 0.0f);
    bool   nval = false;
    if (SORTED && tile < tiles) {
        const int e = tile * 16 + l15;
        nval = (e < n_edges);
        nm = emeta[min(e, n_edges - 1)];
    }

    for (; tile < tiles; tile += tstride) {
        // ---- edge meta: lane handles edge m = l15 (x4 redundant) ----
        int row, col; float dist; bool valid;
        if (SORTED) {
            row = __float_as_int(nm.x); col = __float_as_int(nm.y);
            dist = nm.z; valid = nval;
            // prefetch NEXT tile's meta; consumed one iteration later
            const int tn = tile + tstride;
            if (tn < tiles) {
                const int e = tn * 16 + l15;
                nval = (e < n_edges);
                nm = emeta[min(e, n_edges - 1)];
            }
        } else {
            const int e = tile * 16 + l15;
            valid = (e < n_edges);
            const int eidx = valid ? e : (n_edges - 1);
            row = min(max(ei[eidx], 0), n_nodes - 1);
            col = min(max(ei[n_edges + eidx], 0), n_nodes - 1);
            const float dx = pos[row * 3 + 0] - pos[col * 3 + 0];
            const float dy = pos[row * 3 + 1] - pos[col * 3 + 1];
            const float dz = pos[row * 3 + 2] - pos[col * 3 + 2];
            dist = sqrtf(dx * dx + dy * dy + dz * dz + 1e-8f);
        }
        const float cut = (valid && dist <= CUTOFF)
            ? 0.5f * (__cosf(PI_F * dist * (1.0f / CUTOFF)) + 1.0f) : 0.0f;

        // broadcast to C-layout owners (m = quad*4 + r) via shfl
        int mrow[4], mcol[4]; float mcut[4];
#pragma unroll
        for (int r = 0; r < 4; ++r) {
            const int src = quad * 4 + r;      // lanes 0..15 hold edges 0..15
            if (!SORTED) mrow[r] = __shfl(row, src);
            mcol[r] = __shfl(col, src);
            mcut[r] = __shfl(cut, src);
        }

        // ---- EARLY h gather, packed to bf16 pairs (16 VGPR; the message is
        // rounded to bf16 downstream anyway) ----
        unsigned int hv2[4][4];
#pragma unroll
        for (int r = 0; r < 4; ++r) {
            const float* hp = &h[(size_t)mcol[r] * HIDDEN + l15];
#pragma unroll
            for (int p = 0; p < 4; ++p) {
                const float f0 = hp[p * 32];
                const float f1 = hp[p * 32 + 16];
                hv2[r][p] = ((unsigned int)f2bf(f1) << 16) |
                            (unsigned int)f2bf(f0);
            }
        }

        // ---- A1 fragments: RBFs computed analytically in-register ----
        short8 a1[2];
#pragma unroll
        for (int kit = 0; kit < 2; ++kit) {
            short8 f;
#pragma unroll
            for (int j = 0; j < 8; ++j) {
                const int k = kit * 32 + quad * 8 + j;
                const float x = (dist - OFF_STEP * (float)k) * INV_WIDTH;
                const float rv = (k < NUM_RBF) ? __expf(-0.5f * x * x) : 0.0f;
                f[j] = (short)f2bf(rv);
            }
            a1[kit] = f;
        }

        // ---- layer 1 -> silu -> tbuf (bf16, swizzled); kit-0 B from regs,
        // kit-1 B from LDS ----
#pragma unroll
        for (int nt = 0; nt < 8; ++nt) {
            const short8 bB =
                *(const short8*)&fw1T[swz32(nt * 16 + l15, quad * 8)];
            const float b0 = bfpair(fb1p[nt >> 1], nt & 1);
            floatx4 c = {b0, b0, b0, b0};
            c = __builtin_amdgcn_mfma_f32_16x16x32_bf16(a1[0], b10[nt], c, 0, 0, 0);
            c = __builtin_amdgcn_mfma_f32_16x16x32_bf16(a1[1], bB, c, 0, 0, 0);
#pragma unroll
            for (int r = 0; r < 4; ++r)
                twave[swz(quad * 4 + r, nt * 16 + l15)] = f2bf(silu(c[r]));
        }

        // ---- A2 fragments from tbuf (tbuf free for reuse afterwards) ----
        short8 a2[4];
#pragma unroll
        for (int kit = 0; kit < 4; ++kit)
            a2[kit] = *(const short8*)&twave[swz(l15, kit * 32 + quad * 8)];

        // ---- layer 2 + cutoff*h epilogue ----
#pragma unroll
        for (int nt = 0; nt < 8; ++nt) {
            const float b0 = bfpair(fb2p[nt >> 1], nt & 1);
            floatx4 c = {b0, b0, b0, b0};
#pragma unroll
            for (int kit = 0; kit < 4; ++kit) {
                const short8 b =
                    *(const short8*)&fw2T[swz(nt * 16 + l15, kit * 32 + quad * 8)];
                c = __builtin_amdgcn_mfma_f32_16x16x32_bf16(a2[kit], b, c, 0, 0, 0);
            }
            const int chan = nt * 16 + l15;
#pragma unroll
            for (int r = 0; r < 4; ++r) {
                const float val = c[r] * mcut[r] * bfpair(hv2[r][nt >> 1], nt & 1);
                if (SORTED) {
                    // stage message (bf16) for the segmented walk
                    twave[swz(quad * 4 + r, chan)] = f2bf(val);
                } else {
                    atomicAdd(&agg[mrow[r] * HIDDEN + chan], val);
                }
            }
        }

        if (SORTED) {
            // ---- segmented walk: rows sorted within tile; uniform-branch
            // flush at run boundaries (ballot mask); row lookup via __shfl
            // (index is a compile-time constant).
            const int pr = __shfl(row, (l15 > 0) ? (l15 - 1) : 0);
            const unsigned long long bal =
                __ballot((l15 > 0) && (row != pr));
            const unsigned int mask = (unsigned int)bal & 0xFFFFu;

            const int c0 = lane * 2;          // this lane owns chans c0, c0+1
            float acc0 = 0.0f, acc1 = 0.0f;
            int prow = __shfl(row, 0);
#pragma unroll
            for (int i = 0; i < 16; ++i) {
                const unsigned int bits =
                    *(const unsigned int*)&twave[swz(i, c0)];
                union { unsigned int u; float f; } lo, hi;
                lo.u = bits << 16;            // chan c0
                hi.u = bits & 0xffff0000u;    // chan c0+1
                if (mask & (1u << i)) {       // wave-uniform branch
                    atomicAdd(&agg[prow * HIDDEN + c0],     acc0);
                    atomicAdd(&agg[prow * HIDDEN + c0 + 1], acc1);
                    acc0 = 0.0f; acc1 = 0.0f;
                    prow = __shfl(row, i);
                }
                acc0 += lo.f; acc1 += hi.f;
            }
            atomicAdd(&agg[prow * HIDDEN + c0],     acc0);
            atomicAdd(&agg[prow * HIDDEN + c0 + 1], acc1);
        }
    }
}

// ---------------------------------------------------------------------------
// Node kernel (MFMA): out = h + silu(agg@iw1+b1)@iw2+b2. Grid 256.
// ---------------------------------------------------------------------------
__global__ __launch_bounds__(256) void node_mfma_kernel(
    const float* __restrict__ h,
    const float* __restrict__ agg,
    const float* __restrict__ iw1,
    const float* __restrict__ ib1,
    const float* __restrict__ iw2,
    const float* __restrict__ ib2,
    float* __restrict__ out,
    int n_nodes)
{
    __shared__ __attribute__((aligned(16))) unsigned short w2T[128 * 128];
    __shared__ __attribute__((aligned(16))) unsigned short tbuf[4 * 16 * 128];

    const int tid  = threadIdx.x;
    const int wave = tid >> 6;
    const int lane = tid & 63;
    const int l15  = lane & 15;
    const int quad = lane >> 4;

    for (int idx = tid; idx < HIDDEN * HIDDEN; idx += 256) {
        const int k = idx >> 7, n = idx & 127;
        w2T[swz(n, k)] = f2bf(iw2[idx]);
    }

    short8 b1[4][8];
#pragma unroll
    for (int kit = 0; kit < 4; ++kit)
#pragma unroll
        for (int nt = 0; nt < 8; ++nt) {
            short8 f;
#pragma unroll
            for (int j = 0; j < 8; ++j) {
                const int k = kit * 32 + quad * 8 + j;
                f[j] = (short)f2bf(iw1[k * HIDDEN + nt * 16 + l15]);
            }
            b1[kit][nt] = f;
        }

    float ib1v[8], ib2v[8];
#pragma unroll
    for (int nt = 0; nt < 8; ++nt) {
        ib1v[nt] = ib1[nt * 16 + l15];
        ib2v[nt] = ib2[nt * 16 + l15];
    }

    __syncthreads();

    unsigned short* twave = &tbuf[wave * 16 * 128];
    const int tiles = (n_nodes + 15) >> 4;

    for (int tile = blockIdx.x * 4 + wave; tile < tiles; tile += gridDim.x * 4) {
        const int m0 = tile * 16;

        const int mA = min(m0 + l15, n_nodes - 1);
        short8 a1[4];
#pragma unroll
        for (int kit = 0; kit < 4; ++kit) {
            const float* p = &agg[(size_t)mA * HIDDEN + kit * 32 + quad * 8];
            short8 f;
#pragma unroll
            for (int j = 0; j < 8; ++j) f[j] = (short)f2bf(p[j]);
            a1[kit] = f;
        }

        int mo[4]; float hres[4][8];
#pragma unroll
        for (int r = 0; r < 4; ++r) {
            mo[r] = m0 + quad * 4 + r;
            const int mc = min(mo[r], n_nodes - 1);
#pragma unroll
            for (int nt = 0; nt < 8; ++nt)
                hres[r][nt] = h[(size_t)mc * HIDDEN + nt * 16 + l15];
        }

#pragma unroll
        for (int nt = 0; nt < 8; ++nt) {
            floatx4 c = {ib1v[nt], ib1v[nt], ib1v[nt], ib1v[nt]};
#pragma unroll
            for (int kit = 0; kit < 4; ++kit)
                c = __builtin_amdgcn_mfma_f32_16x16x32_bf16(a1[kit], b1[kit][nt], c, 0, 0, 0);
#pragma unroll
            for (int r = 0; r < 4; ++r)
                twave[swz(quad * 4 + r, nt * 16 + l15)] = f2bf(silu(c[r]));
        }

        short8 a2[4];
#pragma unroll
        for (int kit = 0; kit < 4; ++kit)
            a2[kit] = *(const short8*)&twave[swz(l15, kit * 32 + quad * 8)];

#pragma unroll
        for (int nt = 0; nt < 8; ++nt) {
            floatx4 c = {ib2v[nt], ib2v[nt], ib2v[nt], ib2v[nt]};
#pragma unroll
            for (int kit = 0; kit < 4; ++kit) {
                const short8 b =
                    *(const short8*)&w2T[swz(nt * 16 + l15, kit * 32 + quad * 8)];
                c = __builtin_amdgcn_mfma_f32_16x16x32_bf16(a2[kit], b, c, 0, 0, 0);
            }
            const int chan = nt * 16 + l15;
#pragma unroll
            for (int r = 0; r < 4; ++r)
                if (mo[r] < n_nodes)
                    out[(size_t)mo[r] * HIDDEN + chan] = hres[r][nt] + c[r];
        }
    }
}

extern "C" void kernel_launch(void* const* d_in, const int* in_sizes, int n_in,
                              void* d_out, int out_size, void* d_ws, size_t ws_size,
                              hipStream_t stream)
{
    const float* h   = (const float*)d_in[0];
    const float* pos = (const float*)d_in[1];
    const int*   ei  = (const int*)d_in[2];
    const float* fw1 = (const float*)d_in[3];
    const float* fb1 = (const float*)d_in[4];
    const float* fw2 = (const float*)d_in[5];
    const float* fb2 = (const float*)d_in[6];
    const float* iw1 = (const float*)d_in[7];
    const float* ib1 = (const float*)d_in[8];
    const float* iw2 = (const float*)d_in[9];
    const float* ib2 = (const float*)d_in[10];
    float* out = (float*)d_out;

    const int n_nodes = in_sizes[0] / HIDDEN;
    const int n_edges = in_sizes[2] / 2;
    const int nscan   = (n_nodes + 255) >> 8;   // scanA blocks (<=256 required)

    const size_t need = (size_t)n_nodes * HIDDEN * sizeof(float);
    const bool use_ws = (d_ws != nullptr) && (ws_size >= need);

    // sort scratch layout in d_out (ints): cnt[nb] cursor[nb] btot[256]
    // boff[256] emeta[4*E] (emeta 16B-aligned)
    const size_t moff = (((size_t)2 * n_nodes + 512) + 3) & ~(size_t)3;
    const size_t scratch_ints = moff + (size_t)4 * n_edges;
    const bool can_sort = use_ws && nscan <= 256 &&
                          ((size_t)out_size >= scratch_ints);

    if (can_sort) {
        float*  agg    = (float*)d_ws;
        int*    base   = (int*)d_out;
        int*    cnt    = base;
        int*    cursor = base + n_nodes;
        int*    btot   = base + 2 * n_nodes;
        int*    boff   = btot + 256;
        float4* emeta  = (float4*)(base + moff);

        hipMemsetAsync(cnt, 0, (size_t)n_nodes * sizeof(int), stream);
        hipMemsetAsync(agg, 0, need, stream);

        hist_kernel<<<1024, 256, 0, stream>>>(ei, cnt, n_nodes, n_edges);
        scanA_kernel<<<nscan, 256, 0, stream>>>(cnt, cursor, btot, n_nodes);
        scanB_kernel<<<1, 256, 0, stream>>>(btot, boff, nscan);
        scatter_kernel<<<1024, 256, 0, stream>>>(ei, pos, cursor, boff,
                                                 emeta, n_nodes, n_edges);

        // 512 blocks x 8 waves = 2 blocks/CU resident (single pass)
        edge_mfma_kernel<true><<<512, 512, 0, stream>>>(
            h, pos, ei, emeta,
            fw1, fb1, fw2, fb2, agg, n_nodes, n_edges);

        node_mfma_kernel<<<256, 256, 0, stream>>>(h, agg, iw1, ib1, iw2, ib2,
                                                  out, n_nodes);
    } else {
        float* agg = use_ws ? (float*)d_ws : out;
        hipMemsetAsync(agg, 0, need, stream);
        edge_mfma_kernel<false><<<512, 512, 0, stream>>>(
            h, pos, ei, nullptr,
            fw1, fb1, fw2, fb2, agg, n_nodes, n_edges);
        node_mfma_kernel<<<256, 256, 0, stream>>>(h, agg, iw1, ib1, iw2, ib2,
                                                  out, n_nodes);
    }
}

// Round 4
// 318.730 us; speedup vs baseline: 1.3681x; 1.3681x over previous
//
#include <hip/hip_runtime.h>
#include <hip/hip_bf16.h>

#define HIDDEN  128
#define NUM_RBF 50
#define CUTOFF  5.0f
#define INV_WIDTH (49.0f / 5.0f)
#define OFF_STEP  (5.0f / 49.0f)
#define PI_F 3.14159265358979f

typedef __attribute__((ext_vector_type(8))) short short8;   // 8 bf16 (4 VGPR)
typedef __attribute__((ext_vector_type(4))) float floatx4;  // MFMA acc

// round-half-up bf16 conversion: 2 VALU ops (extra error <= 1/2 ULP on staged
// intermediates only — absmax margin 0.031 vs 0.108 threshold).
__device__ __forceinline__ unsigned short f2bf(float x) {
    union { float f; unsigned int u; } v; v.f = x;
    return (unsigned short)((v.u + 0x8000u) >> 16);
}

// unpack one bf16 of a packed pair to float (hi is compile-time)
__device__ __forceinline__ float bfpair(unsigned int p, int hi) {
    union { unsigned int u; float f; } v;
    v.u = hi ? (p & 0xffff0000u) : (p << 16);
    return v.f;
}

__device__ __forceinline__ float silu(float x) {
    return x / (1.0f + __expf(-x));
}

// XOR-swizzled half-index into a [rows][128] bf16 tile (256B rows): 16B slots
// XORed with row&7 (m201 st_16x32 pattern) — fragment reads land ~2-way
// bank-aliased (free per m136) with NO padding.
__device__ __forceinline__ int swz(int row, int k) {
    return (row << 7) + (((k >> 3) ^ (row & 7)) << 3) + (k & 7);
}

// same for [rows][64] bf16 tiles (128B rows = 32 banks: rows all alias without
// the XOR; row&7 over the 8 16B slots breaks it to ~2-way).
__device__ __forceinline__ int swz64(int row, int k) {
    return (row << 6) + (((k >> 3) ^ (row & 7)) << 3) + (k & 7);
}

// ---------------------------------------------------------------------------
// Counting-sort pipeline (scratch lives in d_out; node kernel overwrites d_out
// only at the very end). Hierarchical scan: local 256-bin scans + top scan.
// ---------------------------------------------------------------------------
__global__ void hist_kernel(const int* __restrict__ ei, int* __restrict__ cnt,
                            int n_nodes, int n_edges)
{
    for (int e = blockIdx.x * blockDim.x + threadIdx.x; e < n_edges;
         e += gridDim.x * blockDim.x) {
        const int r = min(max(ei[e], 0), n_nodes - 1);
        atomicAdd(&cnt[r], 1);
    }
}

__global__ __launch_bounds__(256) void scanA_kernel(const int* __restrict__ cnt,
                                                    int* __restrict__ cursor,
                                                    int* __restrict__ btot,
                                                    int nb)
{
    __shared__ int s[256];
    const int t = threadIdx.x;
    const int i = blockIdx.x * 256 + t;
    const int v = (i < nb) ? cnt[i] : 0;
    s[t] = v;
    __syncthreads();
#pragma unroll
    for (int off = 1; off < 256; off <<= 1) {
        const int u = (t >= off) ? s[t - off] : 0;
        __syncthreads();
        s[t] += u;
        __syncthreads();
    }
    if (i < nb) cursor[i] = s[t] - v;           // local exclusive prefix
    if (t == 255) btot[blockIdx.x] = s[255];    // segment total
}

__global__ __launch_bounds__(256) void scanB_kernel(const int* __restrict__ btot,
                                                    int* __restrict__ boff,
                                                    int nblk)
{
    __shared__ int s[256];
    const int t = threadIdx.x;
    const int v = (t < nblk) ? btot[t] : 0;
    s[t] = v;
    __syncthreads();
#pragma unroll
    for (int off = 1; off < 256; off <<= 1) {
        const int u = (t >= off) ? s[t - off] : 0;
        __syncthreads();
        s[t] += u;
        __syncthreads();
    }
    if (t < nblk) boff[t] = s[t] - v;
}

// One 16B record per sorted edge: {row, col, dist, pad}. Single cache line
// touched per random-position write; the edge kernel's meta prefetch is one
// coalesced float4 load.
__global__ void scatter_kernel(const int* __restrict__ ei,
                               const float* __restrict__ pos,
                               int* __restrict__ cursor,
                               const int* __restrict__ boff,
                               float4* __restrict__ emeta,
                               int n_nodes, int n_edges)
{
    for (int e = blockIdx.x * blockDim.x + threadIdx.x; e < n_edges;
         e += gridDim.x * blockDim.x) {
        const int r = min(max(ei[e], 0), n_nodes - 1);
        const int c = min(max(ei[n_edges + e], 0), n_nodes - 1);
        const float dx = pos[r * 3 + 0] - pos[c * 3 + 0];
        const float dy = pos[r * 3 + 1] - pos[c * 3 + 1];
        const float dz = pos[r * 3 + 2] - pos[c * 3 + 2];
        const float dist = sqrtf(dx * dx + dy * dy + dz * dz + 1e-8f);
        const int p = boff[r >> 8] + atomicAdd(&cursor[r], 1);
        emeta[p] = make_float4(__int_as_float(r), __int_as_float(c), dist, 0.0f);
    }
}

// ---------------------------------------------------------------------------
// Edge kernel: 512 thr = 8 waves sharing fw2T/fw1T; each wave owns 16-edge
// tiles (grid-stride).
// LDS residency cliff (rounds 1-3 measured): <=64KB/block -> 2 blocks/CU
// (occ 46%); 72KB and 80KB -> 1 block (occ 22%). So: fw2T 32KB + fw1T 16KB
// + tbuf 8x2KB = 65536B exactly (round-1's proven-resident size).
// tbuf is halved by processing the 16x128 intermediate in TWO 64-chan halves:
// layer-1 phase A (nt 0..3) -> stage 16x64 -> a2[0..1]; phase B (nt 4..7)
// overwrites -> a2[2..3]; all 4 A2 frags then sit in regs and layer-2 runs
// with a transient accumulator (no persistent c[8] — avoids +32 VGPR).
// The segmented walk runs per-half too (lane owns 1 chan not 2; same atomic
// count, mask computed once).
// Register config = round 2's (all fw1 via LDS): proven zero-spill at the
// 128 cap of __launch_bounds__(512,2) (2nd arg = min BLOCKS/CU, CUDA
// semantics — round-1 post-mortem). Round 3's kit0-in-regs spilled: reverted.
// Spill tripwire: FETCH_SIZE must be ~142MB, WRITE ~87MB.
// ---------------------------------------------------------------------------
template<bool SORTED>
__global__ __launch_bounds__(512, 2) void edge_mfma_kernel(
    const float* __restrict__ h,
    const float* __restrict__ pos,
    const int* __restrict__ ei,
    const float4* __restrict__ emeta,
    const float* __restrict__ fw1,
    const float* __restrict__ fb1,
    const float* __restrict__ fw2,
    const float* __restrict__ fb2,
    float* __restrict__ agg,
    int n_nodes, int n_edges)
{
    __shared__ __attribute__((aligned(16))) unsigned short fw2T[128 * 128];
    __shared__ __attribute__((aligned(16))) unsigned short fw1T[128 * 64];
    __shared__ __attribute__((aligned(16))) unsigned short tbuf[8 * 16 * 64];

    const int tid  = threadIdx.x;
    const int wave = tid >> 6;
    const int lane = tid & 63;
    const int l15  = lane & 15;
    const int quad = lane >> 4;

    // stage fw2 transposed+swizzled (bf16): fw2T[(n,k)] = fw2[k][n]
    for (int idx = tid; idx < HIDDEN * HIDDEN; idx += 512) {
        const int k = idx >> 7, n = idx & 127;
        fw2T[swz(n, k)] = f2bf(fw2[idx]);
    }
    // stage fw1 transposed+swizzled, zero rows k>=50: fw1T[(n,k)] = fw1[k][n]
    for (int idx = tid; idx < HIDDEN * 64; idx += 512) {
        const int n = idx >> 6, k = idx & 63;
        const float v = (k < NUM_RBF) ? fw1[k * HIDDEN + n] : 0.0f;
        fw1T[swz64(n, k)] = f2bf(v);
    }

    // biases packed bf16 (8 VGPR instead of 16)
    unsigned int fb1p[4], fb2p[4];
#pragma unroll
    for (int p = 0; p < 4; ++p) {
        fb1p[p] = ((unsigned int)f2bf(fb1[(p * 2 + 1) * 16 + l15]) << 16) |
                  (unsigned int)f2bf(fb1[(p * 2) * 16 + l15]);
        fb2p[p] = ((unsigned int)f2bf(fb2[(p * 2 + 1) * 16 + l15]) << 16) |
                  (unsigned int)f2bf(fb2[(p * 2) * 16 + l15]);
    }

    __syncthreads();   // fw2T/fw1T ready; no barriers inside the loop

    unsigned short* twave = &tbuf[wave * 16 * 64];
    const int tiles = (n_edges + 15) >> 4;
    const int tstride = gridDim.x * 8;
    int tile = blockIdx.x * 8 + wave;

    // ---- prefetch first tile's meta (sorted path) ----
    float4 nm = make_float4(0.0f, 0.0f, 0.0f, 0.0f);
    bool   nval = false;
    if (SORTED && tile < tiles) {
        const int e = tile * 16 + l15;
        nval = (e < n_edges);
        nm = emeta[min(e, n_edges - 1)];
    }

    for (; tile < tiles; tile += tstride) {
        // ---- edge meta: lane handles edge m = l15 (x4 redundant) ----
        int row, col; float dist; bool valid;
        if (SORTED) {
            row = __float_as_int(nm.x); col = __float_as_int(nm.y);
            dist = nm.z; valid = nval;
            // prefetch NEXT tile's meta; consumed one iteration later
            const int tn = tile + tstride;
            if (tn < tiles) {
                const int e = tn * 16 + l15;
                nval = (e < n_edges);
                nm = emeta[min(e, n_edges - 1)];
            }
        } else {
            const int e = tile * 16 + l15;
            valid = (e < n_edges);
            const int eidx = valid ? e : (n_edges - 1);
            row = min(max(ei[eidx], 0), n_nodes - 1);
            col = min(max(ei[n_edges + eidx], 0), n_nodes - 1);
            const float dx = pos[row * 3 + 0] - pos[col * 3 + 0];
            const float dy = pos[row * 3 + 1] - pos[col * 3 + 1];
            const float dz = pos[row * 3 + 2] - pos[col * 3 + 2];
            dist = sqrtf(dx * dx + dy * dy + dz * dz + 1e-8f);
        }
        const float cut = (valid && dist <= CUTOFF)
            ? 0.5f * (__cosf(PI_F * dist * (1.0f / CUTOFF)) + 1.0f) : 0.0f;

        // broadcast to C-layout owners (m = quad*4 + r) via shfl
        int mrow[4], mcol[4]; float mcut[4];
#pragma unroll
        for (int r = 0; r < 4; ++r) {
            const int src = quad * 4 + r;      // lanes 0..15 hold edges 0..15
            if (!SORTED) mrow[r] = __shfl(row, src);
            mcol[r] = __shfl(col, src);
            mcut[r] = __shfl(cut, src);
        }

        // ---- EARLY h gather, packed to bf16 pairs (16 VGPR; the message is
        // rounded to bf16 downstream anyway) ----
        unsigned int hv2[4][4];
#pragma unroll
        for (int r = 0; r < 4; ++r) {
            const float* hp = &h[(size_t)mcol[r] * HIDDEN + l15];
#pragma unroll
            for (int p = 0; p < 4; ++p) {
                const float f0 = hp[p * 32];
                const float f1 = hp[p * 32 + 16];
                hv2[r][p] = ((unsigned int)f2bf(f1) << 16) |
                            (unsigned int)f2bf(f0);
            }
        }

        // ---- A1 fragments: RBFs computed analytically in-register ----
        short8 a1[2];
#pragma unroll
        for (int kit = 0; kit < 2; ++kit) {
            short8 f;
#pragma unroll
            for (int j = 0; j < 8; ++j) {
                const int k = kit * 32 + quad * 8 + j;
                const float x = (dist - OFF_STEP * (float)k) * INV_WIDTH;
                const float rv = (k < NUM_RBF) ? __expf(-0.5f * x * x) : 0.0f;
                f[j] = (short)f2bf(rv);
            }
            a1[kit] = f;
        }

        // ---- layer 1 -> silu -> tbuf in TWO 64-chan halves; A2 frags pulled
        // into regs after each half (wave-private LDS, DS pipe in-order per
        // wave: the same store->read idiom all prior rounds relied on) ----
        short8 a2[4];
#pragma unroll
        for (int half = 0; half < 2; ++half) {
#pragma unroll
            for (int nt2 = 0; nt2 < 4; ++nt2) {
                const int nt = half * 4 + nt2;
                const short8 bA =
                    *(const short8*)&fw1T[swz64(nt * 16 + l15, quad * 8)];
                const short8 bB =
                    *(const short8*)&fw1T[swz64(nt * 16 + l15, 32 + quad * 8)];
                const float b0 = bfpair(fb1p[nt >> 1], nt & 1);
                floatx4 c = {b0, b0, b0, b0};
                c = __builtin_amdgcn_mfma_f32_16x16x32_bf16(a1[0], bA, c, 0, 0, 0);
                c = __builtin_amdgcn_mfma_f32_16x16x32_bf16(a1[1], bB, c, 0, 0, 0);
#pragma unroll
                for (int r = 0; r < 4; ++r)
                    twave[swz64(quad * 4 + r, nt2 * 16 + l15)] = f2bf(silu(c[r]));
            }
            a2[half * 2]     = *(const short8*)&twave[swz64(l15, quad * 8)];
            a2[half * 2 + 1] = *(const short8*)&twave[swz64(l15, 32 + quad * 8)];
        }

        // ---- walk mask (computed once, used by both half-walks) ----
        unsigned int mask = 0;
        if (SORTED) {
            const int pr = __shfl(row, (l15 > 0) ? (l15 - 1) : 0);
            const unsigned long long bal =
                __ballot((l15 > 0) && (row != pr));
            mask = (unsigned int)bal & 0xFFFFu;
        }

        // ---- layer 2 + cutoff*h epilogue, per 64-chan half; segmented walk
        // after each half (lane owns 1 chan per walk) ----
#pragma unroll
        for (int half = 0; half < 2; ++half) {
#pragma unroll
            for (int nt2 = 0; nt2 < 4; ++nt2) {
                const int nt = half * 4 + nt2;
                const float b0 = bfpair(fb2p[nt >> 1], nt & 1);
                floatx4 c = {b0, b0, b0, b0};
#pragma unroll
                for (int kit = 0; kit < 4; ++kit) {
                    const short8 b =
                        *(const short8*)&fw2T[swz(nt * 16 + l15, kit * 32 + quad * 8)];
                    c = __builtin_amdgcn_mfma_f32_16x16x32_bf16(a2[kit], b, c, 0, 0, 0);
                }
                const int chan = nt * 16 + l15;
#pragma unroll
                for (int r = 0; r < 4; ++r) {
                    const float val = c[r] * mcut[r] * bfpair(hv2[r][nt >> 1], nt & 1);
                    if (SORTED) {
                        twave[swz64(quad * 4 + r, nt2 * 16 + l15)] = f2bf(val);
                    } else {
                        atomicAdd(&agg[mrow[r] * HIDDEN + chan], val);
                    }
                }
            }

            if (SORTED) {
                const int gchan = half * 64 + lane;   // this lane's channel
                float acc = 0.0f;
                int prow = __shfl(row, 0);
#pragma unroll
                for (int i = 0; i < 16; ++i) {
                    union { unsigned int u; float f; } v;
                    v.u = (unsigned int)twave[swz64(i, lane)] << 16;
                    if (mask & (1u << i)) {           // wave-uniform branch
                        atomicAdd(&agg[prow * HIDDEN + gchan], acc);
                        acc = 0.0f;
                        prow = __shfl(row, i);
                    }
                    acc += v.f;
                }
                atomicAdd(&agg[prow * HIDDEN + gchan], acc);
            }
        }
    }
}

// ---------------------------------------------------------------------------
// Node kernel (MFMA): out = h + silu(agg@iw1+b1)@iw2+b2. Grid 256.
// ---------------------------------------------------------------------------
__global__ __launch_bounds__(256) void node_mfma_kernel(
    const float* __restrict__ h,
    const float* __restrict__ agg,
    const float* __restrict__ iw1,
    const float* __restrict__ ib1,
    const float* __restrict__ iw2,
    const float* __restrict__ ib2,
    float* __restrict__ out,
    int n_nodes)
{
    __shared__ __attribute__((aligned(16))) unsigned short w2T[128 * 128];
    __shared__ __attribute__((aligned(16))) unsigned short tbuf[4 * 16 * 128];

    const int tid  = threadIdx.x;
    const int wave = tid >> 6;
    const int lane = tid & 63;
    const int l15  = lane & 15;
    const int quad = lane >> 4;

    for (int idx = tid; idx < HIDDEN * HIDDEN; idx += 256) {
        const int k = idx >> 7, n = idx & 127;
        w2T[swz(n, k)] = f2bf(iw2[idx]);
    }

    short8 b1[4][8];
#pragma unroll
    for (int kit = 0; kit < 4; ++kit)
#pragma unroll
        for (int nt = 0; nt < 8; ++nt) {
            short8 f;
#pragma unroll
            for (int j = 0; j < 8; ++j) {
                const int k = kit * 32 + quad * 8 + j;
                f[j] = (short)f2bf(iw1[k * HIDDEN + nt * 16 + l15]);
            }
            b1[kit][nt] = f;
        }

    float ib1v[8], ib2v[8];
#pragma unroll
    for (int nt = 0; nt < 8; ++nt) {
        ib1v[nt] = ib1[nt * 16 + l15];
        ib2v[nt] = ib2[nt * 16 + l15];
    }

    __syncthreads();

    unsigned short* twave = &tbuf[wave * 16 * 128];
    const int tiles = (n_nodes + 15) >> 4;

    for (int tile = blockIdx.x * 4 + wave; tile < tiles; tile += gridDim.x * 4) {
        const int m0 = tile * 16;

        const int mA = min(m0 + l15, n_nodes - 1);
        short8 a1[4];
#pragma unroll
        for (int kit = 0; kit < 4; ++kit) {
            const float* p = &agg[(size_t)mA * HIDDEN + kit * 32 + quad * 8];
            short8 f;
#pragma unroll
            for (int j = 0; j < 8; ++j) f[j] = (short)f2bf(p[j]);
            a1[kit] = f;
        }

        int mo[4]; float hres[4][8];
#pragma unroll
        for (int r = 0; r < 4; ++r) {
            mo[r] = m0 + quad * 4 + r;
            const int mc = min(mo[r], n_nodes - 1);
#pragma unroll
            for (int nt = 0; nt < 8; ++nt)
                hres[r][nt] = h[(size_t)mc * HIDDEN + nt * 16 + l15];
        }

#pragma unroll
        for (int nt = 0; nt < 8; ++nt) {
            floatx4 c = {ib1v[nt], ib1v[nt], ib1v[nt], ib1v[nt]};
#pragma unroll
            for (int kit = 0; kit < 4; ++kit)
                c = __builtin_amdgcn_mfma_f32_16x16x32_bf16(a1[kit], b1[kit][nt], c, 0, 0, 0);
#pragma unroll
            for (int r = 0; r < 4; ++r)
                twave[swz(quad * 4 + r, nt * 16 + l15)] = f2bf(silu(c[r]));
        }

        short8 a2[4];
#pragma unroll
        for (int kit = 0; kit < 4; ++kit)
            a2[kit] = *(const short8*)&twave[swz(l15, kit * 32 + quad * 8)];

#pragma unroll
        for (int nt = 0; nt < 8; ++nt) {
            floatx4 c = {ib2v[nt], ib2v[nt], ib2v[nt], ib2v[nt]};
#pragma unroll
            for (int kit = 0; kit < 4; ++kit) {
                const short8 b =
                    *(const short8*)&w2T[swz(nt * 16 + l15, kit * 32 + quad * 8)];
                c = __builtin_amdgcn_mfma_f32_16x16x32_bf16(a2[kit], b, c, 0, 0, 0);
            }
            const int chan = nt * 16 + l15;
#pragma unroll
            for (int r = 0; r < 4; ++r)
                if (mo[r] < n_nodes)
                    out[(size_t)mo[r] * HIDDEN + chan] = hres[r][nt] + c[r];
        }
    }
}

extern "C" void kernel_launch(void* const* d_in, const int* in_sizes, int n_in,
                              void* d_out, int out_size, void* d_ws, size_t ws_size,
                              hipStream_t stream)
{
    const float* h   = (const float*)d_in[0];
    const float* pos = (const float*)d_in[1];
    const int*   ei  = (const int*)d_in[2];
    const float* fw1 = (const float*)d_in[3];
    const float* fb1 = (const float*)d_in[4];
    const float* fw2 = (const float*)d_in[5];
    const float* fb2 = (const float*)d_in[6];
    const float* iw1 = (const float*)d_in[7];
    const float* ib1 = (const float*)d_in[8];
    const float* iw2 = (const float*)d_in[9];
    const float* ib2 = (const float*)d_in[10];
    float* out = (float*)d_out;

    const int n_nodes = in_sizes[0] / HIDDEN;
    const int n_edges = in_sizes[2] / 2;
    const int nscan   = (n_nodes + 255) >> 8;   // scanA blocks (<=256 required)

    const size_t need = (size_t)n_nodes * HIDDEN * sizeof(float);
    const bool use_ws = (d_ws != nullptr) && (ws_size >= need);

    // sort scratch layout in d_out (ints): cnt[nb] cursor[nb] btot[256]
    // boff[256] emeta[4*E] (emeta 16B-aligned)
    const size_t moff = (((size_t)2 * n_nodes + 512) + 3) & ~(size_t)3;
    const size_t scratch_ints = moff + (size_t)4 * n_edges;
    const bool can_sort = use_ws && nscan <= 256 &&
                          ((size_t)out_size >= scratch_ints);

    if (can_sort) {
        float*  agg    = (float*)d_ws;
        int*    base   = (int*)d_out;
        int*    cnt    = base;
        int*    cursor = base + n_nodes;
        int*    btot   = base + 2 * n_nodes;
        int*    boff   = btot + 256;
        float4* emeta  = (float4*)(base + moff);

        hipMemsetAsync(cnt, 0, (size_t)n_nodes * sizeof(int), stream);
        hipMemsetAsync(agg, 0, need, stream);

        hist_kernel<<<1024, 256, 0, stream>>>(ei, cnt, n_nodes, n_edges);
        scanA_kernel<<<nscan, 256, 0, stream>>>(cnt, cursor, btot, n_nodes);
        scanB_kernel<<<1, 256, 0, stream>>>(btot, boff, nscan);
        scatter_kernel<<<1024, 256, 0, stream>>>(ei, pos, cursor, boff,
                                                 emeta, n_nodes, n_edges);

        // 512 blocks x 8 waves, 64KB LDS = 2 blocks/CU resident (single pass)
        edge_mfma_kernel<true><<<512, 512, 0, stream>>>(
            h, pos, ei, emeta,
            fw1, fb1, fw2, fb2, agg, n_nodes, n_edges);

        node_mfma_kernel<<<256, 256, 0, stream>>>(h, agg, iw1, ib1, iw2, ib2,
                                                  out, n_nodes);
    } else {
        float* agg = use_ws ? (float*)d_ws : out;
        hipMemsetAsync(agg, 0, need, stream);
        edge_mfma_kernel<false><<<512, 512, 0, stream>>>(
            h, pos, ei, nullptr,
            fw1, fb1, fw2, fb2, agg, n_nodes, n_edges);
        node_mfma_kernel<<<256, 256, 0, stream>>>(h, agg, iw1, ib1, iw2, ib2,
                                                  out, n_nodes);
    }
}